// Round 12
// baseline (360.672 us; speedup 1.0000x reference)
//
#include <hip/hip_runtime.h>
#include <hip/hip_bf16.h>
#include <math.h>

#define Bb 16
#define Cc 512
#define Nn 2048

typedef unsigned short u16;
typedef __attribute__((ext_vector_type(8))) short bf16x8;
typedef __attribute__((ext_vector_type(4))) float f32x4;

typedef __attribute__((address_space(3))) unsigned as3_u32;
typedef __attribute__((address_space(1))) const unsigned as1_u32;

__device__ __forceinline__ float b2f(u16 u){ unsigned x = ((unsigned)u) << 16; return __builtin_bit_cast(float, x); }
__device__ __forceinline__ u16 f2b(float f){
  unsigned x = __builtin_bit_cast(unsigned, f);
  x += 0x7fffu + ((x >> 16) & 1u);
  return (u16)(x >> 16);
}

__device__ __forceinline__ void gload16(const u16* g, u16* l){
  __builtin_amdgcn_global_load_lds((as1_u32*)(uintptr_t)(const void*)g,
                                   (as3_u32*)(uintptr_t)(void*)l, 16, 0, 0);
}

#define BAR() do{ __builtin_amdgcn_s_barrier(); asm volatile("" ::: "memory"); }while(0)
#define WAITV0() asm volatile("s_waitcnt vmcnt(0)" ::: "memory")

// ---------------- weight f32 -> bf16 convert ----------------
__global__ __launch_bounds__(256) void k_cvt(const float* __restrict__ s0, const float* __restrict__ s1,
                                             const float* __restrict__ s2,
                                             u16* __restrict__ d0, u16* __restrict__ d1, u16* __restrict__ d2){
  const float* s = (blockIdx.z == 0) ? s0 : (blockIdx.z == 1) ? s1 : s2;
  u16* d = (blockIdx.z == 0) ? d0 : (blockIdx.z == 1) ? d1 : d2;
  int i = blockIdx.x * 256 + threadIdx.x;
  float4 v = ((const float4*)s)[i];
  ushort4 o; o.x = f2b(v.x); o.y = f2b(v.y); o.z = f2b(v.z); o.w = f2b(v.w);
  ((ushort4*)d)[i] = o;
}

// ---------------- GroupNorm -> h[c][n] (bf16) ----------------
__global__ __launch_bounds__(256) void k_gn(const float* __restrict__ x,
                                            const float* __restrict__ gamma,
                                            const float* __restrict__ beta,
                                            u16* __restrict__ h){
  int bid = blockIdx.x;
  int b = bid >> 5, g = bid & 31;
  const float4* xv = (const float4*)(x + ((size_t)b * Cc + g * 16) * Nn);
  u16* hp = h + ((size_t)b * Cc + g * 16) * Nn;
  int t = threadIdx.x;
  float s = 0.f, ss = 0.f;
#pragma unroll 4
  for (int it = 0; it < 32; ++it){
    float4 v = xv[it * 256 + t];
    s  += v.x + v.y + v.z + v.w;
    ss += v.x * v.x + v.y * v.y + v.z * v.z + v.w * v.w;
  }
#pragma unroll
  for (int o = 32; o >= 1; o >>= 1){ s += __shfl_xor(s, o); ss += __shfl_xor(ss, o); }
  __shared__ float rs[4], rss[4];
  int w = t >> 6;
  if ((t & 63) == 0){ rs[w] = s; rss[w] = ss; }
  __syncthreads();
  s  = rs[0] + rs[1] + rs[2] + rs[3];
  ss = rss[0] + rss[1] + rss[2] + rss[3];
  float mean = s * (1.f / 32768.f);
  float var  = ss * (1.f / 32768.f) - mean * mean;
  float inv  = rsqrtf(var + 1e-6f);
#pragma unroll 4
  for (int it = 0; it < 32; ++it){
    int idx = it * 256 + t;
    float4 u = xv[idx];
    int ch = g * 16 + (idx >> 9);
    float ga = gamma[ch] * inv, be = beta[ch];
    ushort4 o;
    o.x = f2b((u.x - mean) * ga + be);
    o.y = f2b((u.y - mean) * ga + be);
    o.z = f2b((u.z - mean) * ga + be);
    o.w = f2b((u.w - mean) * ga + be);
    ((ushort4*)hp)[idx] = o;
  }
}

// ---------------- transpose h[c][n] -> h_t[n][c] ----------------
__global__ __launch_bounds__(256) void k_tr(const u16* __restrict__ h, u16* __restrict__ ht){
  __shared__ u16 lds[64 * 65];
  int b = blockIdx.z;
  int n0 = blockIdx.x * 64, c0 = blockIdx.y * 64;
  const u16* src = h + (size_t)b * Cc * Nn;
  u16* dst = ht + (size_t)b * Nn * Cc;
  int t = threadIdx.x;
  int jc = (t & 7) << 3;
  int r  = t >> 3;
#pragma unroll
  for (int it = 0; it < 2; ++it){
    int rr = r + it * 32;
    uint4 vv = *(const uint4*)(src + (size_t)(c0 + rr) * Nn + n0 + jc);
    u16* pv = (u16*)&vv;
#pragma unroll
    for (int e = 0; e < 8; ++e) lds[(jc + e) * 65 + rr] = pv[e];
  }
  __syncthreads();
#pragma unroll
  for (int it = 0; it < 2; ++it){
    int rn = r + it * 32;
    u16 tmp[8];
#pragma unroll
    for (int e = 0; e < 8; ++e) tmp[e] = lds[rn * 65 + jc + e];
    *(uint4*)(dst + (size_t)(n0 + rn) * Cc + c0 + jc) = *(const uint4*)tmp;
  }
}

// =====================================================================
// GEMM core: 256x256 / BK=32 / 8-wave / 2-slot dbuf (64 KB -> 2 blk/CU),
// R8's 2-phase interleave, dist-1 prefetch, vmcnt(0) tail (drain covered
// by the co-resident block). Ledger (field-verified in R9, absmax OK):
// ph-a stages A(T+1), ph-b stages B(T+1) into slot (T+1)&1, whose last
// readers drained at T-1's final barrier. Swizzle: 16B-chunk ^ (row>>1)&3
// pre-applied on global src; matching XOR on ds_read (0 conflicts, R3).
// Swapped MFMA operands: acc[i][j]=mfma(b,a) -> packed col stores.
// =====================================================================
#define GSLOT 16384

__device__ __forceinline__ void gemm256(const u16* __restrict__ A, int lda,
                                        const u16* __restrict__ B, int ldb, int K,
                                        u16* __restrict__ lds, f32x4 (&acc)[8][4]){
  const int tid = threadIdx.x;
  const int w = tid >> 6, lane = tid & 63;
  const int lr = lane & 15, lk = lane >> 4;
  const int wr = w >> 2, wc = w & 3;

  const int swzc = lk ^ ((lr >> 1) & 3);
  const int aoff = (wr * 128 + lr) * 32 + 8 * swzc;
  const int boff = 8192 + (wc * 64 + lr) * 32 + 8 * swzc;

  const int idx0 = w * 128 + lane;
  const int idx1 = idx0 + 64;
  const int r0s = idx0 >> 2, r1s = idx1 >> 2;
  const int c0 = (idx0 & 3) ^ ((r0s >> 1) & 3);
  const int c1 = (idx1 & 3) ^ ((r1s >> 1) & 3);
  const u16* gA0 = A + (size_t)r0s * lda + 8 * c0;
  const u16* gA1 = A + (size_t)r1s * lda + 8 * c1;
  const u16* gB0 = B + (size_t)r0s * ldb + 8 * c0;
  const u16* gB1 = B + (size_t)r1s * ldb + 8 * c1;
  const int dst0 = w * 1024;
  const int dst1 = dst0 + 512;

#pragma unroll
  for (int i = 0; i < 8; ++i)
#pragma unroll
    for (int j = 0; j < 4; ++j){ f32x4 z = {0.f,0.f,0.f,0.f}; acc[i][j] = z; }

  const int NT = K >> 5;

  // prologue: tile 0 into slot 0
  gload16(gA0, lds + dst0);        gload16(gA1, lds + dst1);
  gload16(gB0, lds + 8192 + dst0); gload16(gB1, lds + 8192 + dst1);
  WAITV0();
  BAR();

#pragma unroll 1
  for (int T = 0; T < NT; ++T){
    const u16* cur = lds + (T & 1) * GSLOT;
    u16* nxt = lds + ((T + 1) & 1) * GSLOT;
    const bool pf = (T + 1) < NT;
    const int kk = (T + 1) << 5;

    // ---- phase a: read a0/b0 frags; stage A(T+1) ----
    bf16x8 a0[4], b0[4];
#pragma unroll
    for (int i = 0; i < 4; ++i) a0[i] = *(const bf16x8*)(cur + aoff + i * 512);
#pragma unroll
    for (int j = 0; j < 4; ++j) b0[j] = *(const bf16x8*)(cur + boff + j * 512);
    if (pf){ gload16(gA0 + kk, nxt + dst0); gload16(gA1 + kk, nxt + dst1); }
    BAR();
    __builtin_amdgcn_s_setprio(1);
#pragma unroll
    for (int i = 0; i < 4; ++i)
#pragma unroll
      for (int j = 0; j < 4; ++j)
        acc[i][j] = __builtin_amdgcn_mfma_f32_16x16x32_bf16(b0[j], a0[i], acc[i][j], 0, 0, 0);
    __builtin_amdgcn_s_setprio(0);
    BAR();

    // ---- phase b: read a1 frags; stage B(T+1) ----
    bf16x8 a1[4];
#pragma unroll
    for (int i = 0; i < 4; ++i) a1[i] = *(const bf16x8*)(cur + aoff + (i + 4) * 512);
    if (pf){ gload16(gB0 + kk, nxt + 8192 + dst0); gload16(gB1 + kk, nxt + 8192 + dst1); }
    BAR();
    __builtin_amdgcn_s_setprio(1);
#pragma unroll
    for (int i = 0; i < 4; ++i)
#pragma unroll
      for (int j = 0; j < 4; ++j)
        acc[i + 4][j] = __builtin_amdgcn_mfma_f32_16x16x32_bf16(b0[j], a1[i], acc[i + 4][j], 0, 0, 0);
    __builtin_amdgcn_s_setprio(0);
    if (pf) WAITV0();
    BAR();
  }
}

#define EPI_COORDS \
  int lane = threadIdx.x & 63, w = threadIdx.x >> 6; \
  int wr = w >> 2, wc = w & 3; \
  int lr = lane & 15; \
  int lk = lane >> 4; \
  int g4 = lk << 2; \
  (void)lk;

// ---------------- q_t / k_t: [n][co] ----------------
__global__ __launch_bounds__(512, 2) void k_qkt(const u16* __restrict__ ht,
                                                const u16* __restrict__ wqb, const u16* __restrict__ wkb,
                                                const float* __restrict__ bq, const float* __restrict__ bk,
                                                u16* __restrict__ qt, u16* __restrict__ kt){
  __shared__ u16 lds[2 * GSLOT];
  int z = blockIdx.z, b = z >> 1, p = z & 1;
  int m0 = blockIdx.x * 256, n0 = blockIdx.y * 256;
  const u16* A = ht + (size_t)b * Nn * Cc + (size_t)m0 * Cc;
  const u16* B = (p ? wkb : wqb) + (size_t)n0 * Cc;
  const float* bias = p ? bk : bq;
  u16* out = (p ? kt : qt) + (size_t)b * Nn * Cc;
  f32x4 acc[8][4];
  gemm256(A, Cc, B, Cc, Cc, lds, acc);
  EPI_COORDS
#pragma unroll
  for (int i = 0; i < 8; ++i){
    int row = m0 + wr * 128 + i * 16 + lr;
#pragma unroll
    for (int j = 0; j < 4; ++j){
      int coln = n0 + wc * 64 + j * 16 + g4;
      float4 bi = *(const float4*)(bias + coln);
      ushort4 o;
      o.x = f2b(acc[i][j][0] + bi.x);
      o.y = f2b(acc[i][j][1] + bi.y);
      o.z = f2b(acc[i][j][2] + bi.z);
      o.w = f2b(acc[i][j][3] + bi.w);
      *(ushort4*)(out + (size_t)row * Cc + coln) = o;
    }
  }
}

// ---------------- v: [co][n] ----------------
__global__ __launch_bounds__(512, 2) void k_vproj(const u16* __restrict__ wvb, const u16* __restrict__ ht,
                                                  const float* __restrict__ bv, u16* __restrict__ v){
  __shared__ u16 lds[2 * GSLOT];
  int b = blockIdx.z;
  int m0 = blockIdx.x * 256, n0 = blockIdx.y * 256;
  const u16* A = wvb + (size_t)m0 * Cc;
  const u16* B = ht + (size_t)b * Nn * Cc + (size_t)n0 * Cc;
  u16* out = v + (size_t)b * Cc * Nn;
  f32x4 acc[8][4];
  gemm256(A, Cc, B, Cc, Cc, lds, acc);
  EPI_COORDS
#pragma unroll
  for (int i = 0; i < 8; ++i){
    int row = m0 + wr * 128 + i * 16 + lr;
    float bi = bv[row];
#pragma unroll
    for (int j = 0; j < 4; ++j){
      int coln = n0 + wc * 64 + j * 16 + g4;
      ushort4 o;
      o.x = f2b(acc[i][j][0] + bi);
      o.y = f2b(acc[i][j][1] + bi);
      o.z = f2b(acc[i][j][2] + bi);
      o.w = f2b(acc[i][j][3] + bi);
      *(ushort4*)(out + (size_t)row * Nn + coln) = o;
    }
  }
}

// ---------------- scores: P'[nq][m] = exp(scale*q.k); rowsum -> lsum ----------------
__global__ __launch_bounds__(512, 2) void k_scores(const u16* __restrict__ qt, const u16* __restrict__ kt,
                                                   u16* __restrict__ p, float* __restrict__ lsum){
  __shared__ u16 lds[2 * GSLOT];
  __shared__ float sums[256][4];
  int bid = blockIdx.x;                       // 1024 blocks, 1024%8==0
  int swz = (bid & 7) * 128 + (bid >> 3);
  int b = swz >> 6, rem = swz & 63;
  int m0 = (rem & 7) * 256, n0 = (rem >> 3) * 256;
  const u16* A = qt + (size_t)b * Nn * Cc + (size_t)m0 * Cc;
  const u16* B = kt + (size_t)b * Nn * Cc + (size_t)n0 * Cc;
  u16* pb = p + (size_t)b * Nn * Nn;
  f32x4 acc[8][4];
  gemm256(A, Cc, B, Cc, Cc, lds, acc);
  const float scale = 0.044194173824159216f;
  EPI_COORDS
  float psum[8];
#pragma unroll
  for (int i = 0; i < 8; ++i) psum[i] = 0.f;
#pragma unroll
  for (int i = 0; i < 8; ++i){
    int row = m0 + wr * 128 + i * 16 + lr;
#pragma unroll
    for (int j = 0; j < 4; ++j){
      int coln = n0 + wc * 64 + j * 16 + g4;
      float e0 = __expf(acc[i][j][0] * scale);
      float e1 = __expf(acc[i][j][1] * scale);
      float e2 = __expf(acc[i][j][2] * scale);
      float e3 = __expf(acc[i][j][3] * scale);
      psum[i] += (e0 + e1) + (e2 + e3);
      ushort4 o; o.x = f2b(e0); o.y = f2b(e1); o.z = f2b(e2); o.w = f2b(e3);
      *(ushort4*)(pb + (size_t)row * Nn + coln) = o;
    }
  }
#pragma unroll
  for (int i = 0; i < 8; ++i){
    psum[i] += __shfl_xor(psum[i], 16);
    psum[i] += __shfl_xor(psum[i], 32);
  }
  if (lk == 0){
#pragma unroll
    for (int i = 0; i < 8; ++i) sums[wr * 128 + i * 16 + lr][wc] = psum[i];
  }
  __syncthreads();
  int tid = threadIdx.x;
  if (tid < 256){
    float sv = sums[tid][0] + sums[tid][1] + sums[tid][2] + sums[tid][3];
    atomicAdd(lsum + (size_t)b * Nn + m0 + tid, sv);
  }
}

// ---------------- PV: ao_t[nq][c] = (P' v^T)[nq][c] / l[nq] ----------------
__global__ __launch_bounds__(512, 2) void k_pv(const u16* __restrict__ p, const u16* __restrict__ v,
                                               const float* __restrict__ lsum, u16* __restrict__ aot){
  __shared__ u16 lds[2 * GSLOT];
  int bid = blockIdx.x;                       // 256 blocks
  int swz = (bid & 7) * 32 + (bid >> 3);
  int b = swz >> 4, rem = swz & 15;
  int m0 = (rem & 7) * 256, n0 = (rem >> 3) * 256;
  const u16* A = p + (size_t)b * Nn * Nn + (size_t)m0 * Nn;
  const u16* B = v + (size_t)b * Cc * Nn + (size_t)n0 * Nn;
  u16* out = aot + (size_t)b * Nn * Cc;
  f32x4 acc[8][4];
  gemm256(A, Nn, B, Nn, Nn, lds, acc);
  EPI_COORDS
#pragma unroll
  for (int i = 0; i < 8; ++i){
    int row = m0 + wr * 128 + i * 16 + lr;
    float linv = 1.0f / lsum[(size_t)b * Nn + row];
#pragma unroll
    for (int j = 0; j < 4; ++j){
      int coln = n0 + wc * 64 + j * 16 + g4;
      ushort4 o;
      o.x = f2b(acc[i][j][0] * linv);
      o.y = f2b(acc[i][j][1] * linv);
      o.z = f2b(acc[i][j][2] * linv);
      o.w = f2b(acc[i][j][3] * linv);
      *(ushort4*)(out + (size_t)row * Cc + coln) = o;
    }
  }
}

// ---------------- proj + residual (fp32 out, float4 stores) ----------------
__global__ __launch_bounds__(512, 2) void k_proj(const u16* __restrict__ wob, const u16* __restrict__ aot,
                                                 const float* __restrict__ bo, const float* __restrict__ x,
                                                 float* __restrict__ out){
  __shared__ u16 lds[2 * GSLOT];
  int b = blockIdx.z;
  int m0 = blockIdx.x * 256, n0 = blockIdx.y * 256;
  const u16* A = wob + (size_t)m0 * Cc;
  const u16* B = aot + (size_t)b * Nn * Cc + (size_t)n0 * Cc;
  f32x4 acc[8][4];
  gemm256(A, Cc, B, Cc, Cc, lds, acc);
  size_t base = (size_t)b * Cc * Nn;
  EPI_COORDS
#pragma unroll
  for (int i = 0; i < 8; ++i){
    int row = m0 + wr * 128 + i * 16 + lr;
    float bi = bo[row];
#pragma unroll
    for (int j = 0; j < 4; ++j){
      int coln = n0 + wc * 64 + j * 16 + g4;
      size_t idx = base + (size_t)row * Nn + coln;
      float4 xv = *(const float4*)(x + idx);
      float4 o;
      o.x = xv.x + bi + acc[i][j][0];
      o.y = xv.y + bi + acc[i][j][1];
      o.z = xv.z + bi + acc[i][j][2];
      o.w = xv.w + bi + acc[i][j][3];
      *(float4*)(out + idx) = o;
    }
  }
}

extern "C" void kernel_launch(void* const* d_in, const int* in_sizes, int n_in,
                              void* d_out, int out_size, void* d_ws, size_t ws_size,
                              hipStream_t stream){
  const float* x     = (const float*)d_in[0];
  const float* gamma = (const float*)d_in[1];
  const float* beta  = (const float*)d_in[2];
  const float* wq = (const float*)d_in[3];
  const float* bq = (const float*)d_in[4];
  const float* wk = (const float*)d_in[5];
  const float* bk = (const float*)d_in[6];
  const float* wv = (const float*)d_in[7];
  const float* bv = (const float*)d_in[8];
  const float* wo = (const float*)d_in[9];
  const float* bo = (const float*)d_in[10];
  float* out = (float*)d_out;

  char* ws = (char*)d_ws;
  const size_t MB = 1048576ull;
  // P occupies 0..128MB; everything aliased inside it is dead before k_scores.
  u16* P   = (u16*)ws;                  // [b][n][n] bf16, 128MB (written by scores)
  u16* h   = (u16*)ws;                  // 0..32MB   (gn -> tr, dead after tr)
  u16* ht  = (u16*)(ws + 32 * MB);      // 32..64MB  (dead after vproj)
  u16* wqb = (u16*)(ws + 64 * MB);      // dead after qkt
  u16* wkb = wqb + 262144;              // dead after qkt
  u16* wvb = wqb + 524288;              // dead after vproj
  u16* qt  = (u16*)(ws + 128 * MB);     // 32MB (dead after scores; pv writes aot here)
  u16* kt  = (u16*)(ws + 160 * MB);     // 32MB
  u16* v   = (u16*)(ws + 192 * MB);     // 32MB
  u16* wob = (u16*)(ws + 224 * MB);     // 0.5MB, alive until proj
  float* lsum = (float*)(ws + 225 * MB);// 128KB fp32 [b][n]
  u16* aot = qt;

  k_cvt<<<dim3(256, 1, 3), 256, 0, stream>>>(wq, wk, wv, wqb, wkb, wvb);
  k_cvt<<<dim3(256, 1, 1), 256, 0, stream>>>(wo, wo, wo, wob, wob, wob);
  k_gn<<<dim3(512), 256, 0, stream>>>(x, gamma, beta, h);
  k_tr<<<dim3(32, 8, 16), 256, 0, stream>>>(h, ht);
  k_qkt<<<dim3(8, 2, 32), 512, 0, stream>>>(ht, wqb, wkb, bq, bk, qt, kt);
  k_vproj<<<dim3(2, 8, 16), 512, 0, stream>>>(wvb, ht, bv, v);
  hipMemsetAsync(lsum, 0, (size_t)Bb * Nn * sizeof(float), stream);
  k_scores<<<dim3(1024), 512, 0, stream>>>(qt, kt, P, lsum);
  k_pv<<<dim3(256), 512, 0, stream>>>(P, v, lsum, aot);
  k_proj<<<dim3(2, 8, 16), 512, 0, stream>>>(wob, aot, bo, x, out);
}

// Round 13
// 328.040 us; speedup vs baseline: 1.0995x; 1.0995x over previous
//
#include <hip/hip_runtime.h>
#include <hip/hip_bf16.h>
#include <math.h>

#define Bb 16
#define Cc 512
#define Nn 2048

typedef unsigned short u16;
typedef __attribute__((ext_vector_type(8))) short bf16x8;
typedef __attribute__((ext_vector_type(4))) float f32x4;

typedef __attribute__((address_space(3))) unsigned as3_u32;
typedef __attribute__((address_space(1))) const unsigned as1_u32;

__device__ __forceinline__ float b2f(u16 u){ unsigned x = ((unsigned)u) << 16; return __builtin_bit_cast(float, x); }
__device__ __forceinline__ u16 f2b(float f){
  unsigned x = __builtin_bit_cast(unsigned, f);
  x += 0x7fffu + ((x >> 16) & 1u);
  return (u16)(x >> 16);
}

__device__ __forceinline__ void gload16(const u16* g, u16* l){
  __builtin_amdgcn_global_load_lds((as1_u32*)(uintptr_t)(const void*)g,
                                   (as3_u32*)(uintptr_t)(void*)l, 16, 0, 0);
}

#define BAR() do{ __builtin_amdgcn_s_barrier(); asm volatile("" ::: "memory"); }while(0)
#define WAITV4() asm volatile("s_waitcnt vmcnt(4)" ::: "memory")
#define WAITV0() asm volatile("s_waitcnt vmcnt(0)" ::: "memory")

// ---------------- weight f32 -> bf16 convert (all 4 weights, one launch) ----------------
__global__ __launch_bounds__(256) void k_cvt4(const float* __restrict__ s0, const float* __restrict__ s1,
                                              const float* __restrict__ s2, const float* __restrict__ s3,
                                              u16* __restrict__ d0, u16* __restrict__ d1,
                                              u16* __restrict__ d2, u16* __restrict__ d3){
  int z = blockIdx.z;
  const float* s = (z == 0) ? s0 : (z == 1) ? s1 : (z == 2) ? s2 : s3;
  u16* d = (z == 0) ? d0 : (z == 1) ? d1 : (z == 2) ? d2 : d3;
  int i = blockIdx.x * 256 + threadIdx.x;
  float4 v = ((const float4*)s)[i];
  ushort4 o; o.x = f2b(v.x); o.y = f2b(v.y); o.z = f2b(v.z); o.w = f2b(v.w);
  ((ushort4*)d)[i] = o;
}

// ---------------- GroupNorm -> h[c][n] (bf16) ----------------
__global__ __launch_bounds__(256) void k_gn(const float* __restrict__ x,
                                            const float* __restrict__ gamma,
                                            const float* __restrict__ beta,
                                            u16* __restrict__ h){
  int bid = blockIdx.x;
  int b = bid >> 5, g = bid & 31;
  const float4* xv = (const float4*)(x + ((size_t)b * Cc + g * 16) * Nn);
  u16* hp = h + ((size_t)b * Cc + g * 16) * Nn;
  int t = threadIdx.x;
  float s = 0.f, ss = 0.f;
#pragma unroll 4
  for (int it = 0; it < 32; ++it){
    float4 v = xv[it * 256 + t];
    s  += v.x + v.y + v.z + v.w;
    ss += v.x * v.x + v.y * v.y + v.z * v.z + v.w * v.w;
  }
#pragma unroll
  for (int o = 32; o >= 1; o >>= 1){ s += __shfl_xor(s, o); ss += __shfl_xor(ss, o); }
  __shared__ float rs[4], rss[4];
  int w = t >> 6;
  if ((t & 63) == 0){ rs[w] = s; rss[w] = ss; }
  __syncthreads();
  s  = rs[0] + rs[1] + rs[2] + rs[3];
  ss = rss[0] + rss[1] + rss[2] + rss[3];
  float mean = s * (1.f / 32768.f);
  float var  = ss * (1.f / 32768.f) - mean * mean;
  float inv  = rsqrtf(var + 1e-6f);
#pragma unroll 4
  for (int it = 0; it < 32; ++it){
    int idx = it * 256 + t;
    float4 u = xv[idx];
    int ch = g * 16 + (idx >> 9);
    float ga = gamma[ch] * inv, be = beta[ch];
    ushort4 o;
    o.x = f2b((u.x - mean) * ga + be);
    o.y = f2b((u.y - mean) * ga + be);
    o.z = f2b((u.z - mean) * ga + be);
    o.w = f2b((u.w - mean) * ga + be);
    ((ushort4*)hp)[idx] = o;
  }
}

// ---------------- transpose h[c][n] -> h_t[n][c] ----------------
__global__ __launch_bounds__(256) void k_tr(const u16* __restrict__ h, u16* __restrict__ ht){
  __shared__ u16 lds[64 * 65];
  int b = blockIdx.z;
  int n0 = blockIdx.x * 64, c0 = blockIdx.y * 64;
  const u16* src = h + (size_t)b * Cc * Nn;
  u16* dst = ht + (size_t)b * Nn * Cc;
  int t = threadIdx.x;
  int jc = (t & 7) << 3;
  int r  = t >> 3;
#pragma unroll
  for (int it = 0; it < 2; ++it){
    int rr = r + it * 32;
    uint4 vv = *(const uint4*)(src + (size_t)(c0 + rr) * Nn + n0 + jc);
    u16* pv = (u16*)&vv;
#pragma unroll
    for (int e = 0; e < 8; ++e) lds[(jc + e) * 65 + rr] = pv[e];
  }
  __syncthreads();
#pragma unroll
  for (int it = 0; it < 2; ++it){
    int rn = r + it * 32;
    u16 tmp[8];
#pragma unroll
    for (int e = 0; e < 8; ++e) tmp[e] = lds[rn * 65 + jc + e];
    *(uint4*)(dst + (size_t)(n0 + rn) * Cc + c0 + jc) = *(const uint4*)tmp;
  }
}

// =====================================================================
// R11 GEMM core (best measured): 256x256 / BK=64 / 8-wave / 2-buffer
// (128 KB LDS), 4 phases per K-tile, counted vmcnt(4) once per tile.
// Stage ledger: (T,ph0)->B1(T+1), (T,ph1)->A1(T+1), (T,ph2)->B0(T+2),
// (T,ph3)->A0(T+2). Swizzle: chunk ^= row&7 (full 3-bit), inverse on
// global src. Swapped MFMA operands -> packed col stores.
// =====================================================================
#define GSLOT 32768

__device__ __forceinline__ void gemm256(const u16* __restrict__ A, int lda,
                                        const u16* __restrict__ B, int ldb, int K,
                                        u16* __restrict__ lds, f32x4 (&acc)[8][4]){
  const int tid = threadIdx.x;
  const int w = tid >> 6, lane = tid & 63;
  const int lr = lane & 15, lk = lane >> 4;
  const int wr = w >> 2, wc = w & 3;

  const int sw0 = ((lk    ) ^ (lr & 7)) << 3;
  const int sw1 = ((lk + 4) ^ (lr & 7)) << 3;
  const int arow = (wr * 128 + lr) * 64;
  const int brow = 16384 + (wc * 64 + lr) * 64;

  const int r0 = tid >> 3, c0 = tid & 7;
  const size_t offA0 = (size_t)r0 * lda + (size_t)((c0 ^ (r0 & 7)) << 3);
  const size_t offA1 = offA0 + (size_t)64 * lda;
  const size_t offB0 = (size_t)r0 * ldb + (size_t)((c0 ^ (r0 & 7)) << 3);
  const size_t offB1 = offB0 + (size_t)64 * ldb;
  const int d0 = tid * 8, d1 = tid * 8 + 4096;

#define STGA(h, T, bu) do{ const u16* gp = A + (size_t)(T) * 64 + (size_t)(h) * 128 * lda; \
    u16* lp = lds + (bu) * GSLOT + (h) * 8192; \
    gload16(gp + offA0, lp + d0); gload16(gp + offA1, lp + d1); }while(0)
#define STGB(h, T, bu) do{ const u16* gp = B + (size_t)(T) * 64 + (size_t)(h) * 128 * ldb; \
    u16* lp = lds + (bu) * GSLOT + 16384 + (h) * 8192; \
    gload16(gp + offB0, lp + d0); gload16(gp + offB1, lp + d1); }while(0)

#pragma unroll
  for (int i = 0; i < 8; ++i)
#pragma unroll
    for (int j = 0; j < 4; ++j){ f32x4 z = {0.f,0.f,0.f,0.f}; acc[i][j] = z; }

  const int NT = K >> 6;

  STGA(0, 0, 0); STGA(1, 0, 0); STGB(0, 0, 0); STGB(1, 0, 0);
  if (NT > 1){ STGB(0, 1, 1); STGA(0, 1, 1); WAITV4(); }
  else { WAITV0(); }
  BAR();

  bf16x8 a[4][2], b[4][2];

#pragma unroll 1
  for (int T = 0; T < NT; ++T){
    const u16* cur = lds + (T & 1) * GSLOT;
    const int nb = (T + 1) & 1, cb = T & 1;
    const bool p1 = (T + 1) < NT, p2 = (T + 2) < NT;

    // ---- ph0: read a0-3, b0-1 ; stage B1(T+1) ----
#pragma unroll
    for (int i = 0; i < 4; ++i){
      a[i][0] = *(const bf16x8*)(cur + arow + i * 1024 + sw0);
      a[i][1] = *(const bf16x8*)(cur + arow + i * 1024 + sw1);
    }
#pragma unroll
    for (int j = 0; j < 2; ++j){
      b[j][0] = *(const bf16x8*)(cur + brow + j * 1024 + sw0);
      b[j][1] = *(const bf16x8*)(cur + brow + j * 1024 + sw1);
    }
    if (p1) STGB(1, T + 1, nb);
    BAR();
    __builtin_amdgcn_s_setprio(1);
#pragma unroll
    for (int i = 0; i < 4; ++i)
#pragma unroll
      for (int j = 0; j < 2; ++j)
#pragma unroll
        for (int ks = 0; ks < 2; ++ks)
          acc[i][j] = __builtin_amdgcn_mfma_f32_16x16x32_bf16(b[j][ks], a[i][ks], acc[i][j], 0, 0, 0);
    __builtin_amdgcn_s_setprio(0);
    BAR();

    // ---- ph1: read b2-3 ; stage A1(T+1) ----
#pragma unroll
    for (int j = 2; j < 4; ++j){
      b[j][0] = *(const bf16x8*)(cur + brow + j * 1024 + sw0);
      b[j][1] = *(const bf16x8*)(cur + brow + j * 1024 + sw1);
    }
    if (p1) STGA(1, T + 1, nb);
    BAR();
    __builtin_amdgcn_s_setprio(1);
#pragma unroll
    for (int i = 0; i < 4; ++i)
#pragma unroll
      for (int j = 2; j < 4; ++j)
#pragma unroll
        for (int ks = 0; ks < 2; ++ks)
          acc[i][j] = __builtin_amdgcn_mfma_f32_16x16x32_bf16(b[j][ks], a[i][ks], acc[i][j], 0, 0, 0);
    __builtin_amdgcn_s_setprio(0);
    BAR();

    // ---- ph2: read a4-7 ; stage B0(T+2) ----
#pragma unroll
    for (int i = 0; i < 4; ++i){
      a[i][0] = *(const bf16x8*)(cur + arow + 4096 + i * 1024 + sw0);
      a[i][1] = *(const bf16x8*)(cur + arow + 4096 + i * 1024 + sw1);
    }
    if (p2) STGB(0, T + 2, cb);
    BAR();
    __builtin_amdgcn_s_setprio(1);
#pragma unroll
    for (int i = 0; i < 4; ++i)
#pragma unroll
      for (int j = 0; j < 2; ++j)
#pragma unroll
        for (int ks = 0; ks < 2; ++ks)
          acc[4 + i][j] = __builtin_amdgcn_mfma_f32_16x16x32_bf16(b[j][ks], a[i][ks], acc[4 + i][j], 0, 0, 0);
    __builtin_amdgcn_s_setprio(0);
    BAR();

    // ---- ph3: no reads ; stage A0(T+2) ; counted vmcnt after MFMA ----
    if (p2) STGA(0, T + 2, cb);
    BAR();
    __builtin_amdgcn_s_setprio(1);
#pragma unroll
    for (int i = 0; i < 4; ++i)
#pragma unroll
      for (int j = 2; j < 4; ++j)
#pragma unroll
        for (int ks = 0; ks < 2; ++ks)
          acc[4 + i][j] = __builtin_amdgcn_mfma_f32_16x16x32_bf16(b[j][ks], a[i][ks], acc[4 + i][j], 0, 0, 0);
    __builtin_amdgcn_s_setprio(0);
    if (p2){ WAITV4(); } else if (p1){ WAITV0(); }
    BAR();
  }
#undef STGA
#undef STGB
}

#define EPI_COORDS \
  int lane = threadIdx.x & 63, w = threadIdx.x >> 6; \
  int wr = w >> 2, wc = w & 3; \
  int lr = lane & 15; \
  int lk = lane >> 4; \
  int g4 = lk << 2; \
  (void)lk;

// ---------------- merged q/k/v projections (768 blocks, XCD-chunked) ----------------
// id < 512: q_t/k_t [n][co] = ht . w^T + b ; id >= 512: v [co][n] = w . ht^T + b
__global__ __launch_bounds__(512, 2) void k_qkv(const u16* __restrict__ ht,
                                                const u16* __restrict__ wqb, const u16* __restrict__ wkb,
                                                const u16* __restrict__ wvb,
                                                const float* __restrict__ bq, const float* __restrict__ bk,
                                                const float* __restrict__ bv,
                                                u16* __restrict__ qt, u16* __restrict__ kt,
                                                u16* __restrict__ v){
  __shared__ u16 lds[2 * GSLOT];
  int bid = blockIdx.x;                        // 768 blocks, 768%8==0
  int id = (bid & 7) * 96 + (bid >> 3);        // XCD-chunked
  f32x4 acc[8][4];
  if (id < 512){
    int b = id >> 5, r = id & 31;
    int p = r >> 4, t = r & 15;
    int m0 = (t & 7) * 256, n0 = (t >> 3) * 256;
    const u16* A = ht + (size_t)b * Nn * Cc + (size_t)m0 * Cc;
    const u16* B = (p ? wkb : wqb) + (size_t)n0 * Cc;
    const float* bias = p ? bk : bq;
    u16* out = (p ? kt : qt) + (size_t)b * Nn * Cc;
    gemm256(A, Cc, B, Cc, Cc, lds, acc);
    EPI_COORDS
#pragma unroll
    for (int i = 0; i < 8; ++i){
      int row = m0 + wr * 128 + i * 16 + lr;
#pragma unroll
      for (int j = 0; j < 4; ++j){
        int coln = n0 + wc * 64 + j * 16 + g4;
        float4 bi = *(const float4*)(bias + coln);
        ushort4 o;
        o.x = f2b(acc[i][j][0] + bi.x);
        o.y = f2b(acc[i][j][1] + bi.y);
        o.z = f2b(acc[i][j][2] + bi.z);
        o.w = f2b(acc[i][j][3] + bi.w);
        *(ushort4*)(out + (size_t)row * Cc + coln) = o;
      }
    }
  } else {
    int u = id - 512;                          // 0..255
    int b = u >> 4, r = u & 15;
    int m0 = (r & 1) * 256, n0 = (r >> 1) * 256;
    const u16* A = wvb + (size_t)m0 * Cc;
    const u16* B = ht + (size_t)b * Nn * Cc + (size_t)n0 * Cc;
    u16* out = v + (size_t)b * Cc * Nn;
    gemm256(A, Cc, B, Cc, Cc, lds, acc);
    EPI_COORDS
#pragma unroll
    for (int i = 0; i < 8; ++i){
      int row = m0 + wr * 128 + i * 16 + lr;
      float bi = bv[row];
#pragma unroll
      for (int j = 0; j < 4; ++j){
        int coln = n0 + wc * 64 + j * 16 + g4;
        ushort4 o;
        o.x = f2b(acc[i][j][0] + bi);
        o.y = f2b(acc[i][j][1] + bi);
        o.z = f2b(acc[i][j][2] + bi);
        o.w = f2b(acc[i][j][3] + bi);
        *(ushort4*)(out + (size_t)row * Nn + coln) = o;
      }
    }
  }
}

// ---------------- scores: P'[nq][m] = exp(scale*q.k); rowsum -> lsum ----------------
__global__ __launch_bounds__(512, 2) void k_scores(const u16* __restrict__ qt, const u16* __restrict__ kt,
                                                   u16* __restrict__ p, float* __restrict__ lsum){
  __shared__ u16 lds[2 * GSLOT];
  __shared__ float sums[256][4];
  int bid = blockIdx.x;                       // 1024 blocks, 1024%8==0
  int swz = (bid & 7) * 128 + (bid >> 3);
  int b = swz >> 6, rem = swz & 63;
  int m0 = (rem & 7) * 256, n0 = (rem >> 3) * 256;
  const u16* A = qt + (size_t)b * Nn * Cc + (size_t)m0 * Cc;
  const u16* B = kt + (size_t)b * Nn * Cc + (size_t)n0 * Cc;
  u16* pb = p + (size_t)b * Nn * Nn;
  f32x4 acc[8][4];
  gemm256(A, Cc, B, Cc, Cc, lds, acc);
  const float scale = 0.044194173824159216f;
  EPI_COORDS
  float psum[8];
#pragma unroll
  for (int i = 0; i < 8; ++i) psum[i] = 0.f;
#pragma unroll
  for (int i = 0; i < 8; ++i){
    int row = m0 + wr * 128 + i * 16 + lr;
#pragma unroll
    for (int j = 0; j < 4; ++j){
      int coln = n0 + wc * 64 + j * 16 + g4;
      float e0 = __expf(acc[i][j][0] * scale);
      float e1 = __expf(acc[i][j][1] * scale);
      float e2 = __expf(acc[i][j][2] * scale);
      float e3 = __expf(acc[i][j][3] * scale);
      psum[i] += (e0 + e1) + (e2 + e3);
      ushort4 o; o.x = f2b(e0); o.y = f2b(e1); o.z = f2b(e2); o.w = f2b(e3);
      *(ushort4*)(pb + (size_t)row * Nn + coln) = o;
    }
  }
#pragma unroll
  for (int i = 0; i < 8; ++i){
    psum[i] += __shfl_xor(psum[i], 16);
    psum[i] += __shfl_xor(psum[i], 32);
  }
  if (lk == 0){
#pragma unroll
    for (int i = 0; i < 8; ++i) sums[wr * 128 + i * 16 + lr][wc] = psum[i];
  }
  __syncthreads();
  int tid = threadIdx.x;
  if (tid < 256){
    float sv = sums[tid][0] + sums[tid][1] + sums[tid][2] + sums[tid][3];
    atomicAdd(lsum + (size_t)b * Nn + m0 + tid, sv);
  }
}

// ---------------- PV: ao_t[nq][c] = (P' v^T)[nq][c] / l[nq] ----------------
__global__ __launch_bounds__(512, 2) void k_pv(const u16* __restrict__ p, const u16* __restrict__ v,
                                               const float* __restrict__ lsum, u16* __restrict__ aot){
  __shared__ u16 lds[2 * GSLOT];
  int bid = blockIdx.x;                       // 256 blocks
  int swz = (bid & 7) * 32 + (bid >> 3);
  int b = swz >> 4, rem = swz & 15;
  int m0 = (rem & 7) * 256, n0 = (rem >> 3) * 256;
  const u16* A = p + (size_t)b * Nn * Nn + (size_t)m0 * Nn;
  const u16* B = v + (size_t)b * Cc * Nn + (size_t)n0 * Nn;
  u16* out = aot + (size_t)b * Nn * Cc;
  f32x4 acc[8][4];
  gemm256(A, Nn, B, Nn, Nn, lds, acc);
  EPI_COORDS
#pragma unroll
  for (int i = 0; i < 8; ++i){
    int row = m0 + wr * 128 + i * 16 + lr;
    float linv = 1.0f / lsum[(size_t)b * Nn + row];
#pragma unroll
    for (int j = 0; j < 4; ++j){
      int coln = n0 + wc * 64 + j * 16 + g4;
      ushort4 o;
      o.x = f2b(acc[i][j][0] * linv);
      o.y = f2b(acc[i][j][1] * linv);
      o.z = f2b(acc[i][j][2] * linv);
      o.w = f2b(acc[i][j][3] * linv);
      *(ushort4*)(out + (size_t)row * Cc + coln) = o;
    }
  }
}

// ---------------- proj + residual (fp32 out, float4 stores) ----------------
__global__ __launch_bounds__(512, 2) void k_proj(const u16* __restrict__ wob, const u16* __restrict__ aot,
                                                 const float* __restrict__ bo, const float* __restrict__ x,
                                                 float* __restrict__ out){
  __shared__ u16 lds[2 * GSLOT];
  int b = blockIdx.z;
  int m0 = blockIdx.x * 256, n0 = blockIdx.y * 256;
  const u16* A = wob + (size_t)m0 * Cc;
  const u16* B = aot + (size_t)b * Nn * Cc + (size_t)n0 * Cc;
  f32x4 acc[8][4];
  gemm256(A, Cc, B, Cc, Cc, lds, acc);
  size_t base = (size_t)b * Cc * Nn;
  EPI_COORDS
#pragma unroll
  for (int i = 0; i < 8; ++i){
    int row = m0 + wr * 128 + i * 16 + lr;
    float bi = bo[row];
#pragma unroll
    for (int j = 0; j < 4; ++j){
      int coln = n0 + wc * 64 + j * 16 + g4;
      size_t idx = base + (size_t)row * Nn + coln;
      float4 xv = *(const float4*)(x + idx);
      float4 o;
      o.x = xv.x + bi + acc[i][j][0];
      o.y = xv.y + bi + acc[i][j][1];
      o.z = xv.z + bi + acc[i][j][2];
      o.w = xv.w + bi + acc[i][j][3];
      *(float4*)(out + idx) = o;
    }
  }
}

extern "C" void kernel_launch(void* const* d_in, const int* in_sizes, int n_in,
                              void* d_out, int out_size, void* d_ws, size_t ws_size,
                              hipStream_t stream){
  const float* x     = (const float*)d_in[0];
  const float* gamma = (const float*)d_in[1];
  const float* beta  = (const float*)d_in[2];
  const float* wq = (const float*)d_in[3];
  const float* bq = (const float*)d_in[4];
  const float* wk = (const float*)d_in[5];
  const float* bk = (const float*)d_in[6];
  const float* wv = (const float*)d_in[7];
  const float* bv = (const float*)d_in[8];
  const float* wo = (const float*)d_in[9];
  const float* bo = (const float*)d_in[10];
  float* out = (float*)d_out;

  char* ws = (char*)d_ws;
  const size_t MB = 1048576ull;
  // P occupies 0..128MB; everything aliased inside it is dead before k_scores.
  u16* P   = (u16*)ws;                  // [b][n][n] bf16, 128MB (written by scores)
  u16* h   = (u16*)ws;                  // 0..32MB   (gn -> tr, dead after tr)
  u16* ht  = (u16*)(ws + 32 * MB);      // 32..64MB  (dead after qkv)
  u16* wqb = (u16*)(ws + 64 * MB);      // dead after qkv
  u16* wkb = wqb + 262144;
  u16* wvb = wqb + 524288;
  u16* qt  = (u16*)(ws + 128 * MB);     // 32MB (dead after scores; pv writes aot here)
  u16* kt  = (u16*)(ws + 160 * MB);     // 32MB
  u16* v   = (u16*)(ws + 192 * MB);     // 32MB
  u16* wob = (u16*)(ws + 224 * MB);     // 0.5MB, alive until proj
  float* lsum = (float*)(ws + 225 * MB);// 128KB fp32 [b][n]
  u16* aot = qt;

  k_cvt4<<<dim3(256, 1, 4), 256, 0, stream>>>(wq, wk, wv, wo, wqb, wkb, wvb, wob);
  k_gn<<<dim3(512), 256, 0, stream>>>(x, gamma, beta, h);
  k_tr<<<dim3(32, 8, 16), 256, 0, stream>>>(h, ht);
  k_qkv<<<dim3(768), 512, 0, stream>>>(ht, wqb, wkb, wvb, bq, bk, bv, qt, kt, v);
  hipMemsetAsync(lsum, 0, (size_t)Bb * Nn * sizeof(float), stream);
  k_scores<<<dim3(1024), 512, 0, stream>>>(qt, kt, P, lsum);
  k_pv<<<dim3(256), 512, 0, stream>>>(P, v, lsum, aot);
  k_proj<<<dim3(2, 8, 16), 512, 0, stream>>>(wob, aot, bo, x, out);
}

// Round 14
// 306.414 us; speedup vs baseline: 1.1771x; 1.0706x over previous
//
#include <hip/hip_runtime.h>
#include <hip/hip_bf16.h>
#include <math.h>

#define Bb 16
#define Cc 512
#define Nn 2048

typedef unsigned short u16;
typedef unsigned char u8;
typedef __attribute__((ext_vector_type(8))) short bf16x8;
typedef __attribute__((ext_vector_type(4))) float f32x4;

typedef __attribute__((address_space(3))) unsigned as3_u32;
typedef __attribute__((address_space(1))) const unsigned as1_u32;

__device__ __forceinline__ float b2f(u16 u){ unsigned x = ((unsigned)u) << 16; return __builtin_bit_cast(float, x); }
__device__ __forceinline__ u16 f2b(float f){
  unsigned x = __builtin_bit_cast(unsigned, f);
  x += 0x7fffu + ((x >> 16) & 1u);
  return (u16)(x >> 16);
}

// f32 (>=0) -> fp8 e4m3 (OCP), round-to-nearest-even, sub-2^-6 -> 0, clamp 448
__device__ __forceinline__ unsigned f2e4m3(float f){
  unsigned y = __builtin_bit_cast(unsigned, f);
  if (y < 0x3C800000u) return 0u;
  unsigned r = y - (120u << 23);
  unsigned v = (r + 0x7FFFFu + ((r >> 20) & 1u)) >> 20;
  return v > 0x7Eu ? 0x7Eu : v;
}
// signed variant for V
__device__ __forceinline__ unsigned f2e4m3s(float f){
  unsigned y = __builtin_bit_cast(unsigned, f);
  unsigned s = (y >> 24) & 0x80u;
  y &= 0x7FFFFFFFu;
  if (y < 0x3C800000u) return s;
  unsigned r = y - (120u << 23);
  unsigned v = (r + 0x7FFFFu + ((r >> 20) & 1u)) >> 20;
  return s | (v > 0x7Eu ? 0x7Eu : v);
}

__device__ __forceinline__ void gload16(const u16* g, u16* l){
  __builtin_amdgcn_global_load_lds((as1_u32*)(uintptr_t)(const void*)g,
                                   (as3_u32*)(uintptr_t)(void*)l, 16, 0, 0);
}
__device__ __forceinline__ void gload16b(const u8* g, u8* l){
  __builtin_amdgcn_global_load_lds((as1_u32*)(uintptr_t)(const void*)g,
                                   (as3_u32*)(uintptr_t)(void*)l, 16, 0, 0);
}

#define BAR() do{ __builtin_amdgcn_s_barrier(); asm volatile("" ::: "memory"); }while(0)
#define WAITV4() asm volatile("s_waitcnt vmcnt(4)" ::: "memory")
#define WAITV2() asm volatile("s_waitcnt vmcnt(2)" ::: "memory")
#define WAITV0() asm volatile("s_waitcnt vmcnt(0)" ::: "memory")

// ---------------- weight f32 -> bf16 convert (all 4 weights, one launch) ----------------
__global__ __launch_bounds__(256) void k_cvt4(const float* __restrict__ s0, const float* __restrict__ s1,
                                              const float* __restrict__ s2, const float* __restrict__ s3,
                                              u16* __restrict__ d0, u16* __restrict__ d1,
                                              u16* __restrict__ d2, u16* __restrict__ d3){
  int z = blockIdx.z;
  const float* s = (z == 0) ? s0 : (z == 1) ? s1 : (z == 2) ? s2 : s3;
  u16* d = (z == 0) ? d0 : (z == 1) ? d1 : (z == 2) ? d2 : d3;
  int i = blockIdx.x * 256 + threadIdx.x;
  float4 v = ((const float4*)s)[i];
  ushort4 o; o.x = f2b(v.x); o.y = f2b(v.y); o.z = f2b(v.z); o.w = f2b(v.w);
  ((ushort4*)d)[i] = o;
}

// ---------------- GroupNorm -> h[c][n] (bf16) ----------------
__global__ __launch_bounds__(256) void k_gn(const float* __restrict__ x,
                                            const float* __restrict__ gamma,
                                            const float* __restrict__ beta,
                                            u16* __restrict__ h){
  int bid = blockIdx.x;
  int b = bid >> 5, g = bid & 31;
  const float4* xv = (const float4*)(x + ((size_t)b * Cc + g * 16) * Nn);
  u16* hp = h + ((size_t)b * Cc + g * 16) * Nn;
  int t = threadIdx.x;
  float s = 0.f, ss = 0.f;
#pragma unroll 4
  for (int it = 0; it < 32; ++it){
    float4 v = xv[it * 256 + t];
    s  += v.x + v.y + v.z + v.w;
    ss += v.x * v.x + v.y * v.y + v.z * v.z + v.w * v.w;
  }
#pragma unroll
  for (int o = 32; o >= 1; o >>= 1){ s += __shfl_xor(s, o); ss += __shfl_xor(ss, o); }
  __shared__ float rs[4], rss[4];
  int w = t >> 6;
  if ((t & 63) == 0){ rs[w] = s; rss[w] = ss; }
  __syncthreads();
  s  = rs[0] + rs[1] + rs[2] + rs[3];
  ss = rss[0] + rss[1] + rss[2] + rss[3];
  float mean = s * (1.f / 32768.f);
  float var  = ss * (1.f / 32768.f) - mean * mean;
  float inv  = rsqrtf(var + 1e-6f);
#pragma unroll 4
  for (int it = 0; it < 32; ++it){
    int idx = it * 256 + t;
    float4 u = xv[idx];
    int ch = g * 16 + (idx >> 9);
    float ga = gamma[ch] * inv, be = beta[ch];
    ushort4 o;
    o.x = f2b((u.x - mean) * ga + be);
    o.y = f2b((u.y - mean) * ga + be);
    o.z = f2b((u.z - mean) * ga + be);
    o.w = f2b((u.w - mean) * ga + be);
    ((ushort4*)hp)[idx] = o;
  }
}

// ---------------- transpose h[c][n] -> h_t[n][c] ----------------
__global__ __launch_bounds__(256) void k_tr(const u16* __restrict__ h, u16* __restrict__ ht){
  __shared__ u16 lds[64 * 65];
  int b = blockIdx.z;
  int n0 = blockIdx.x * 64, c0 = blockIdx.y * 64;
  const u16* src = h + (size_t)b * Cc * Nn;
  u16* dst = ht + (size_t)b * Nn * Cc;
  int t = threadIdx.x;
  int jc = (t & 7) << 3;
  int r  = t >> 3;
#pragma unroll
  for (int it = 0; it < 2; ++it){
    int rr = r + it * 32;
    uint4 vv = *(const uint4*)(src + (size_t)(c0 + rr) * Nn + n0 + jc);
    u16* pv = (u16*)&vv;
#pragma unroll
    for (int e = 0; e < 8; ++e) lds[(jc + e) * 65 + rr] = pv[e];
  }
  __syncthreads();
#pragma unroll
  for (int it = 0; it < 2; ++it){
    int rn = r + it * 32;
    u16 tmp[8];
#pragma unroll
    for (int e = 0; e < 8; ++e) tmp[e] = lds[rn * 65 + jc + e];
    *(uint4*)(dst + (size_t)(n0 + rn) * Cc + c0 + jc) = *(const uint4*)tmp;
  }
}

// =====================================================================
// R11/R13 bf16 GEMM core: 256x256 / BK=64 / 8-wave / 2-buffer (128 KB),
// 4 phases per K-tile, counted vmcnt(4). Swizzle chunk^=row&7, inverse
// on global src. Swapped MFMA operands -> packed col stores.
// =====================================================================
#define GSLOT 32768

__device__ __forceinline__ void gemm256(const u16* __restrict__ A, int lda,
                                        const u16* __restrict__ B, int ldb, int K,
                                        u16* __restrict__ lds, f32x4 (&acc)[8][4]){
  const int tid = threadIdx.x;
  const int w = tid >> 6, lane = tid & 63;
  const int lr = lane & 15, lk = lane >> 4;
  const int wr = w >> 2, wc = w & 3;

  const int sw0 = ((lk    ) ^ (lr & 7)) << 3;
  const int sw1 = ((lk + 4) ^ (lr & 7)) << 3;
  const int arow = (wr * 128 + lr) * 64;
  const int brow = 16384 + (wc * 64 + lr) * 64;

  const int r0 = tid >> 3, c0 = tid & 7;
  const size_t offA0 = (size_t)r0 * lda + (size_t)((c0 ^ (r0 & 7)) << 3);
  const size_t offA1 = offA0 + (size_t)64 * lda;
  const size_t offB0 = (size_t)r0 * ldb + (size_t)((c0 ^ (r0 & 7)) << 3);
  const size_t offB1 = offB0 + (size_t)64 * ldb;
  const int d0 = tid * 8, d1 = tid * 8 + 4096;

#define STGA(h, T, bu) do{ const u16* gp = A + (size_t)(T) * 64 + (size_t)(h) * 128 * lda; \
    u16* lp = lds + (bu) * GSLOT + (h) * 8192; \
    gload16(gp + offA0, lp + d0); gload16(gp + offA1, lp + d1); }while(0)
#define STGB(h, T, bu) do{ const u16* gp = B + (size_t)(T) * 64 + (size_t)(h) * 128 * ldb; \
    u16* lp = lds + (bu) * GSLOT + 16384 + (h) * 8192; \
    gload16(gp + offB0, lp + d0); gload16(gp + offB1, lp + d1); }while(0)

#pragma unroll
  for (int i = 0; i < 8; ++i)
#pragma unroll
    for (int j = 0; j < 4; ++j){ f32x4 z = {0.f,0.f,0.f,0.f}; acc[i][j] = z; }

  const int NT = K >> 6;

  STGA(0, 0, 0); STGA(1, 0, 0); STGB(0, 0, 0); STGB(1, 0, 0);
  if (NT > 1){ STGB(0, 1, 1); STGA(0, 1, 1); WAITV4(); }
  else { WAITV0(); }
  BAR();

  bf16x8 a[4][2], b[4][2];

#pragma unroll 1
  for (int T = 0; T < NT; ++T){
    const u16* cur = lds + (T & 1) * GSLOT;
    const int nb = (T + 1) & 1, cb = T & 1;
    const bool p1 = (T + 1) < NT, p2 = (T + 2) < NT;

#pragma unroll
    for (int i = 0; i < 4; ++i){
      a[i][0] = *(const bf16x8*)(cur + arow + i * 1024 + sw0);
      a[i][1] = *(const bf16x8*)(cur + arow + i * 1024 + sw1);
    }
#pragma unroll
    for (int j = 0; j < 2; ++j){
      b[j][0] = *(const bf16x8*)(cur + brow + j * 1024 + sw0);
      b[j][1] = *(const bf16x8*)(cur + brow + j * 1024 + sw1);
    }
    if (p1) STGB(1, T + 1, nb);
    BAR();
    __builtin_amdgcn_s_setprio(1);
#pragma unroll
    for (int i = 0; i < 4; ++i)
#pragma unroll
      for (int j = 0; j < 2; ++j)
#pragma unroll
        for (int ks = 0; ks < 2; ++ks)
          acc[i][j] = __builtin_amdgcn_mfma_f32_16x16x32_bf16(b[j][ks], a[i][ks], acc[i][j], 0, 0, 0);
    __builtin_amdgcn_s_setprio(0);
    BAR();

#pragma unroll
    for (int j = 2; j < 4; ++j){
      b[j][0] = *(const bf16x8*)(cur + brow + j * 1024 + sw0);
      b[j][1] = *(const bf16x8*)(cur + brow + j * 1024 + sw1);
    }
    if (p1) STGA(1, T + 1, nb);
    BAR();
    __builtin_amdgcn_s_setprio(1);
#pragma unroll
    for (int i = 0; i < 4; ++i)
#pragma unroll
      for (int j = 2; j < 4; ++j)
#pragma unroll
        for (int ks = 0; ks < 2; ++ks)
          acc[i][j] = __builtin_amdgcn_mfma_f32_16x16x32_bf16(b[j][ks], a[i][ks], acc[i][j], 0, 0, 0);
    __builtin_amdgcn_s_setprio(0);
    BAR();

#pragma unroll
    for (int i = 0; i < 4; ++i){
      a[i][0] = *(const bf16x8*)(cur + arow + 4096 + i * 1024 + sw0);
      a[i][1] = *(const bf16x8*)(cur + arow + 4096 + i * 1024 + sw1);
    }
    if (p2) STGB(0, T + 2, cb);
    BAR();
    __builtin_amdgcn_s_setprio(1);
#pragma unroll
    for (int i = 0; i < 4; ++i)
#pragma unroll
      for (int j = 0; j < 2; ++j)
#pragma unroll
        for (int ks = 0; ks < 2; ++ks)
          acc[4 + i][j] = __builtin_amdgcn_mfma_f32_16x16x32_bf16(b[j][ks], a[i][ks], acc[4 + i][j], 0, 0, 0);
    __builtin_amdgcn_s_setprio(0);
    BAR();

    if (p2) STGA(0, T + 2, cb);
    BAR();
    __builtin_amdgcn_s_setprio(1);
#pragma unroll
    for (int i = 0; i < 4; ++i)
#pragma unroll
      for (int j = 2; j < 4; ++j)
#pragma unroll
        for (int ks = 0; ks < 2; ++ks)
          acc[4 + i][j] = __builtin_amdgcn_mfma_f32_16x16x32_bf16(b[j][ks], a[i][ks], acc[4 + i][j], 0, 0, 0);
    __builtin_amdgcn_s_setprio(0);
    if (p2){ WAITV4(); } else if (p1){ WAITV0(); }
    BAR();
  }
#undef STGA
#undef STGB
}

#define EPI_COORDS \
  int lane = threadIdx.x & 63, w = threadIdx.x >> 6; \
  int wr = w >> 2, wc = w & 3; \
  int lr = lane & 15; \
  int lk = lane >> 4; \
  int g4 = lk << 2; \
  (void)lk;

// ---------------- merged q/k/v projections (768 blocks, XCD-chunked) ----------------
__global__ __launch_bounds__(512, 2) void k_qkv(const u16* __restrict__ ht,
                                                const u16* __restrict__ wqb, const u16* __restrict__ wkb,
                                                const u16* __restrict__ wvb,
                                                const float* __restrict__ bq, const float* __restrict__ bk,
                                                const float* __restrict__ bv,
                                                u16* __restrict__ qt, u16* __restrict__ kt,
                                                u8* __restrict__ v){
  __shared__ u16 lds[2 * GSLOT];
  int bid = blockIdx.x;                        // 768 blocks
  int id = (bid & 7) * 96 + (bid >> 3);        // XCD-chunked
  f32x4 acc[8][4];
  if (id < 512){
    int b = id >> 5, r = id & 31;
    int p = r >> 4, t = r & 15;
    int m0 = (t & 7) * 256, n0 = (t >> 3) * 256;
    const u16* A = ht + (size_t)b * Nn * Cc + (size_t)m0 * Cc;
    const u16* B = (p ? wkb : wqb) + (size_t)n0 * Cc;
    const float* bias = p ? bk : bq;
    u16* out = (p ? kt : qt) + (size_t)b * Nn * Cc;
    gemm256(A, Cc, B, Cc, Cc, lds, acc);
    EPI_COORDS
#pragma unroll
    for (int i = 0; i < 8; ++i){
      int row = m0 + wr * 128 + i * 16 + lr;
#pragma unroll
      for (int j = 0; j < 4; ++j){
        int coln = n0 + wc * 64 + j * 16 + g4;
        float4 bi = *(const float4*)(bias + coln);
        ushort4 o;
        o.x = f2b(acc[i][j][0] + bi.x);
        o.y = f2b(acc[i][j][1] + bi.y);
        o.z = f2b(acc[i][j][2] + bi.z);
        o.w = f2b(acc[i][j][3] + bi.w);
        *(ushort4*)(out + (size_t)row * Cc + coln) = o;
      }
    }
  } else {
    int u = id - 512;                          // 0..255
    int b = u >> 4, r = u & 15;
    int m0 = (r & 1) * 256, n0 = (r >> 1) * 256;
    const u16* A = wvb + (size_t)m0 * Cc;
    const u16* B = ht + (size_t)b * Nn * Cc + (size_t)n0 * Cc;
    u8* out = v + (size_t)b * Cc * Nn;         // fp8 [c][n]
    gemm256(A, Cc, B, Cc, Cc, lds, acc);
    EPI_COORDS
#pragma unroll
    for (int i = 0; i < 8; ++i){
      int row = m0 + wr * 128 + i * 16 + lr;
      float bi = bv[row];
#pragma unroll
      for (int j = 0; j < 4; ++j){
        int coln = n0 + wc * 64 + j * 16 + g4;
        unsigned o = f2e4m3s(acc[i][j][0] + bi)
                   | (f2e4m3s(acc[i][j][1] + bi) << 8)
                   | (f2e4m3s(acc[i][j][2] + bi) << 16)
                   | (f2e4m3s(acc[i][j][3] + bi) << 24);
        *(unsigned*)(out + (size_t)row * Nn + coln) = o;
      }
    }
  }
}

// ---------------- scores: P'[nq][m] = fp8(exp(scale*q.k)); rowsum -> lsum ----------------
__global__ __launch_bounds__(512, 2) void k_scores(const u16* __restrict__ qt, const u16* __restrict__ kt,
                                                   u8* __restrict__ p, float* __restrict__ lsum){
  __shared__ u16 lds[2 * GSLOT];
  __shared__ float sums[256][4];
  int bid = blockIdx.x;                       // 1024 blocks
  int swz = (bid & 7) * 128 + (bid >> 3);
  int b = swz >> 6, rem = swz & 63;
  int m0 = (rem & 7) * 256, n0 = (rem >> 3) * 256;
  const u16* A = qt + (size_t)b * Nn * Cc + (size_t)m0 * Cc;
  const u16* B = kt + (size_t)b * Nn * Cc + (size_t)n0 * Cc;
  u8* pb = p + (size_t)b * Nn * Nn;
  f32x4 acc[8][4];
  gemm256(A, Cc, B, Cc, Cc, lds, acc);
  const float scale = 0.044194173824159216f;
  EPI_COORDS
  float psum[8];
#pragma unroll
  for (int i = 0; i < 8; ++i) psum[i] = 0.f;
#pragma unroll
  for (int i = 0; i < 8; ++i){
    int row = m0 + wr * 128 + i * 16 + lr;
#pragma unroll
    for (int j = 0; j < 4; ++j){
      int coln = n0 + wc * 64 + j * 16 + g4;
      float e0 = __expf(acc[i][j][0] * scale);
      float e1 = __expf(acc[i][j][1] * scale);
      float e2 = __expf(acc[i][j][2] * scale);
      float e3 = __expf(acc[i][j][3] * scale);
      psum[i] += (e0 + e1) + (e2 + e3);
      unsigned o = f2e4m3(e0) | (f2e4m3(e1) << 8) | (f2e4m3(e2) << 16) | (f2e4m3(e3) << 24);
      *(unsigned*)(pb + (size_t)row * Nn + coln) = o;
    }
  }
#pragma unroll
  for (int i = 0; i < 8; ++i){
    psum[i] += __shfl_xor(psum[i], 16);
    psum[i] += __shfl_xor(psum[i], 32);
  }
  if (lk == 0){
#pragma unroll
    for (int i = 0; i < 8; ++i) sums[wr * 128 + i * 16 + lr][wc] = psum[i];
  }
  __syncthreads();
  int tid = threadIdx.x;
  if (tid < 256){
    float sv = sums[tid][0] + sums[tid][1] + sums[tid][2] + sums[tid][3];
    atomicAdd(lsum + (size_t)b * Nn + m0 + tid, sv);
  }
}

// ---------------- PV (fp8 x fp8): ao_t[nq][c] = (P' v^T)/l ----------------
// 256x256 / BK=64 / 4-phase / 2-buffer, fp8 operands: LDS 2x32 KB.
// Rows are 64 B (4 x 16B chunks); swizzle chunk ^= (row&3)^((row>>2)&3)
// -> b64 fragment reads 2-way (free); inverse applied on global src.
__global__ __launch_bounds__(512, 2) void k_pv(const u8* __restrict__ p, const u8* __restrict__ v,
                                               const float* __restrict__ lsum, u16* __restrict__ aot){
  __shared__ u8 lds[2 * 32768];
  int bid = blockIdx.x;                       // 256 blocks
  int swz = (bid & 7) * 32 + (bid >> 3);
  int b = swz >> 4, rem = swz & 15;
  int m0 = (rem & 7) * 256, n0 = (rem >> 3) * 256;
  const u8* A = p + (size_t)b * Nn * Nn + (size_t)m0 * Nn;
  const u8* B = v + (size_t)b * Cc * Nn + (size_t)n0 * Nn;
  u16* out = aot + (size_t)b * Nn * Cc;

  const int tid = threadIdx.x;
  const int w = tid >> 6, lane = tid & 63;
  const int lr = lane & 15, lk = lane >> 4;
  const int wr = w >> 2, wc = w & 3;

  // fragment byte offsets (precomputed -> registers)
  int aofs[8][2], bofs[4][2];
#pragma unroll
  for (int i = 0; i < 8; ++i){
    int row = wr * 128 + i * 16 + lr;
    int sz = (row & 3) ^ ((row >> 2) & 3);
#pragma unroll
    for (int ks = 0; ks < 2; ++ks)
      aofs[i][ks] = row * 64 + ((((ks << 1) | (lk >> 1)) ^ sz) << 4) + ((lk & 1) << 3);
  }
#pragma unroll
  for (int j = 0; j < 4; ++j){
    int row = wc * 64 + j * 16 + lr;
    int sz = (row & 3) ^ ((row >> 2) & 3);
#pragma unroll
    for (int ks = 0; ks < 2; ++ks)
      bofs[j][ks] = 16384 + row * 64 + ((((ks << 1) | (lk >> 1)) ^ sz) << 4) + ((lk & 1) << 3);
  }

  // staging: 1 x 16B chunk per thread per half-tile (128 rows x 64 B)
  const int srow = tid >> 2, sc = tid & 3;
  const int ssz = (srow & 3) ^ ((srow >> 2) & 3);
  const size_t offS = (size_t)srow * Nn + (size_t)((sc ^ ssz) << 4);
  const int sdst = tid * 16;

#define PSTGA(h, T, bu) gload16b(A + (size_t)(T) * 64 + (size_t)(h) * 128 * Nn + offS, \
                                 lds + (bu) * 32768 + (h) * 8192 + sdst)
#define PSTGB(h, T, bu) gload16b(B + (size_t)(T) * 64 + (size_t)(h) * 128 * Nn + offS, \
                                 lds + (bu) * 32768 + 16384 + (h) * 8192 + sdst)

  f32x4 acc[8][4];
#pragma unroll
  for (int i = 0; i < 8; ++i)
#pragma unroll
    for (int j = 0; j < 4; ++j){ f32x4 z = {0.f,0.f,0.f,0.f}; acc[i][j] = z; }

  const int NT = Nn >> 6;   // 32

  PSTGA(0, 0, 0); PSTGA(1, 0, 0); PSTGB(0, 0, 0); PSTGB(1, 0, 0);
  PSTGB(0, 1, 1); PSTGA(0, 1, 1);
  WAITV2();
  BAR();

  long a[4][2], bf[4][2];

#pragma unroll 1
  for (int T = 0; T < NT; ++T){
    const u8* cur = lds + (T & 1) * 32768;
    const int nb = (T + 1) & 1, cb = T & 1;
    const bool p1 = (T + 1) < NT, p2 = (T + 2) < NT;

    // ph0: read a0-3, b0-1 ; stage B1(T+1)
#pragma unroll
    for (int i = 0; i < 4; ++i){
      a[i][0] = *(const long*)(cur + aofs[i][0]);
      a[i][1] = *(const long*)(cur + aofs[i][1]);
    }
#pragma unroll
    for (int j = 0; j < 2; ++j){
      bf[j][0] = *(const long*)(cur + bofs[j][0]);
      bf[j][1] = *(const long*)(cur + bofs[j][1]);
    }
    if (p1) PSTGB(1, T + 1, nb);
    BAR();
    __builtin_amdgcn_s_setprio(1);
#pragma unroll
    for (int i = 0; i < 4; ++i)
#pragma unroll
      for (int j = 0; j < 2; ++j)
#pragma unroll
        for (int ks = 0; ks < 2; ++ks)
          acc[i][j] = __builtin_amdgcn_mfma_f32_16x16x32_fp8_fp8(bf[j][ks], a[i][ks], acc[i][j], 0, 0, 0);
    __builtin_amdgcn_s_setprio(0);
    BAR();

    // ph1: read b2-3 ; stage A1(T+1)
#pragma unroll
    for (int j = 2; j < 4; ++j){
      bf[j][0] = *(const long*)(cur + bofs[j][0]);
      bf[j][1] = *(const long*)(cur + bofs[j][1]);
    }
    if (p1) PSTGA(1, T + 1, nb);
    BAR();
    __builtin_amdgcn_s_setprio(1);
#pragma unroll
    for (int i = 0; i < 4; ++i)
#pragma unroll
      for (int j = 2; j < 4; ++j)
#pragma unroll
        for (int ks = 0; ks < 2; ++ks)
          acc[i][j] = __builtin_amdgcn_mfma_f32_16x16x32_fp8_fp8(bf[j][ks], a[i][ks], acc[i][j], 0, 0, 0);
    __builtin_amdgcn_s_setprio(0);
    BAR();

    // ph2: read a4-7 ; stage B0(T+2)
#pragma unroll
    for (int i = 0; i < 4; ++i){
      a[i][0] = *(const long*)(cur + aofs[4 + i][0]);
      a[i][1] = *(const long*)(cur + aofs[4 + i][1]);
    }
    if (p2) PSTGB(0, T + 2, cb);
    BAR();
    __builtin_amdgcn_s_setprio(1);
#pragma unroll
    for (int i = 0; i < 4; ++i)
#pragma unroll
      for (int j = 0; j < 2; ++j)
#pragma unroll
        for (int ks = 0; ks < 2; ++ks)
          acc[4 + i][j] = __builtin_amdgcn_mfma_f32_16x16x32_fp8_fp8(bf[j][ks], a[i][ks], acc[4 + i][j], 0, 0, 0);
    __builtin_amdgcn_s_setprio(0);
    BAR();

    // ph3: stage A0(T+2) ; counted vmcnt after MFMA
    if (p2) PSTGA(0, T + 2, cb);
    BAR();
    __builtin_amdgcn_s_setprio(1);
#pragma unroll
    for (int i = 0; i < 4; ++i)
#pragma unroll
      for (int j = 2; j < 4; ++j)
#pragma unroll
        for (int ks = 0; ks < 2; ++ks)
          acc[4 + i][j] = __builtin_amdgcn_mfma_f32_16x16x32_fp8_fp8(bf[j][ks], a[i][ks], acc[4 + i][j], 0, 0, 0);
    __builtin_amdgcn_s_setprio(0);
    if (p2){ WAITV2(); } else if (p1){ WAITV0(); }
    BAR();
  }
#undef PSTGA
#undef PSTGB

  int g4 = lk << 2;
#pragma unroll
  for (int i = 0; i < 8; ++i){
    int row = m0 + wr * 128 + i * 16 + lr;
    float linv = 1.0f / lsum[(size_t)b * Nn + row];
#pragma unroll
    for (int j = 0; j < 4; ++j){
      int coln = n0 + wc * 64 + j * 16 + g4;
      ushort4 o;
      o.x = f2b(acc[i][j][0] * linv);
      o.y = f2b(acc[i][j][1] * linv);
      o.z = f2b(acc[i][j][2] * linv);
      o.w = f2b(acc[i][j][3] * linv);
      *(ushort4*)(out + (size_t)row * Cc + coln) = o;
    }
  }
}

// ---------------- proj + residual (fp32 out, float4 stores) ----------------
__global__ __launch_bounds__(512, 2) void k_proj(const u16* __restrict__ wob, const u16* __restrict__ aot,
                                                 const float* __restrict__ bo, const float* __restrict__ x,
                                                 float* __restrict__ out){
  __shared__ u16 lds[2 * GSLOT];
  int b = blockIdx.z;
  int m0 = blockIdx.x * 256, n0 = blockIdx.y * 256;
  const u16* A = wob + (size_t)m0 * Cc;
  const u16* B = aot + (size_t)b * Nn * Cc + (size_t)n0 * Cc;
  f32x4 acc[8][4];
  gemm256(A, Cc, B, Cc, Cc, lds, acc);
  size_t base = (size_t)b * Cc * Nn;
  EPI_COORDS
#pragma unroll
  for (int i = 0; i < 8; ++i){
    int row = m0 + wr * 128 + i * 16 + lr;
    float bi = bo[row];
#pragma unroll
    for (int j = 0; j < 4; ++j){
      int coln = n0 + wc * 64 + j * 16 + g4;
      size_t idx = base + (size_t)row * Nn + coln;
      float4 xv = *(const float4*)(x + idx);
      float4 o;
      o.x = xv.x + bi + acc[i][j][0];
      o.y = xv.y + bi + acc[i][j][1];
      o.z = xv.z + bi + acc[i][j][2];
      o.w = xv.w + bi + acc[i][j][3];
      *(float4*)(out + idx) = o;
    }
  }
}

extern "C" void kernel_launch(void* const* d_in, const int* in_sizes, int n_in,
                              void* d_out, int out_size, void* d_ws, size_t ws_size,
                              hipStream_t stream){
  const float* x     = (const float*)d_in[0];
  const float* gamma = (const float*)d_in[1];
  const float* beta  = (const float*)d_in[2];
  const float* wq = (const float*)d_in[3];
  const float* bq = (const float*)d_in[4];
  const float* wk = (const float*)d_in[5];
  const float* bk = (const float*)d_in[6];
  const float* wv = (const float*)d_in[7];
  const float* bv = (const float*)d_in[8];
  const float* wo = (const float*)d_in[9];
  const float* bo = (const float*)d_in[10];
  float* out = (float*)d_out;

  char* ws = (char*)d_ws;
  const size_t MB = 1048576ull;
  // P (fp8) occupies 0..64MB; h (0..32) and ht (32..64) are dead before scores.
  u8*  P   = (u8*)ws;                   // [b][n][n] fp8, 64MB
  u16* h   = (u16*)ws;                  // 0..32MB (gn -> tr)
  u16* ht  = (u16*)(ws + 32 * MB);      // 32..64MB (dead after qkv)
  u16* wqb = (u16*)(ws + 64 * MB);
  u16* wkb = wqb + 262144;
  u16* wvb = wqb + 524288;
  u16* qt  = (u16*)(ws + 128 * MB);     // 32MB (dead after scores; pv writes aot here)
  u16* kt  = (u16*)(ws + 160 * MB);     // 32MB
  u8*  v   = (u8*)(ws + 192 * MB);      // 16MB fp8 [c][n]
  u16* wob = (u16*)(ws + 224 * MB);
  float* lsum = (float*)(ws + 225 * MB);// 128KB fp32 [b][n]
  u16* aot = qt;

  k_cvt4<<<dim3(256, 1, 4), 256, 0, stream>>>(wq, wk, wv, wo, wqb, wkb, wvb, wob);
  k_gn<<<dim3(512), 256, 0, stream>>>(x, gamma, beta, h);
  k_tr<<<dim3(32, 8, 16), 256, 0, stream>>>(h, ht);
  k_qkv<<<dim3(768), 512, 0, stream>>>(ht, wqb, wkb, wvb, bq, bk, bv, qt, kt, v);
  hipMemsetAsync(lsum, 0, (size_t)Bb * Nn * sizeof(float), stream);
  k_scores<<<dim3(1024), 512, 0, stream>>>(qt, kt, P, lsum);
  k_pv<<<dim3(256), 512, 0, stream>>>(P, v, lsum, aot);
  k_proj<<<dim3(2, 8, 16), 512, 0, stream>>>(wob, aot, bo, x, out);
}